// Round 2
// baseline (6966.154 us; speedup 1.0000x reference)
//
#include <hip/hip_runtime.h>
#include <cstdint>

// R2: crash theory = workspace overflow (371MB used, ws_size unchecked).
// Restructure: commuted aggregation (agg x then GEMM) + bf16 storage + MFMA GEMM.
// Total ws need: ~157MB. Guard returns no-op if ws_size smaller (diagnostic).

constexpr int H_HEADS = 3;
constexpr float NEG_SLOPE = 0.2f;
constexpr float LN_EPS = 1e-5f;
constexpr int N_MOL = 40000, E_MOL = 80000, C_MOL = 512, G_MOL = 512;
constexpr int N_PROT = 8000, E_PROT = 64000, C_PROT = 1280, G_PROT = 32;
constexpr int LAYERS = 4;

typedef unsigned short u16;
typedef __attribute__((ext_vector_type(8))) short short8v;
typedef __attribute__((ext_vector_type(4))) float f32x4;

__device__ __forceinline__ float bf2f(u16 s) {
    union { unsigned u; float f; } v; v.u = ((unsigned)s) << 16; return v.f;
}
__device__ __forceinline__ u16 f2bf(float f) {
    union { float f; unsigned u; } v; v.f = f;
    return (u16)((v.u + 0x7fffu + ((v.u >> 16) & 1u)) >> 16);
}

// ---------------- small utility kernels ----------------

__global__ void set_int_kernel(int* p, int v, int n) {
    int i = blockIdx.x * blockDim.x + threadIdx.x;
    if (i < n) p[i] = v;
}

__global__ void copy_int_kernel(const int* __restrict__ s, int* __restrict__ d, int n) {
    int i = blockIdx.x * blockDim.x + threadIdx.x;
    if (i < n) d[i] = s[i];
}

__global__ void hist_kernel(const int* __restrict__ keys, int n, int* __restrict__ cnt) {
    int i = blockIdx.x * blockDim.x + threadIdx.x;
    if (i < n) atomicAdd(&cnt[keys[i]], 1);
}

// single-block exclusive scan; out has n+1 entries (out[n] = total)
__global__ void scan_kernel(const int* __restrict__ in, int* __restrict__ out, int n) {
    __shared__ int sums[1024];
    const int t = threadIdx.x;
    const int chunk = (n + 1023) / 1024;
    const int start = t * chunk;
    const int end = min(start + chunk, n);
    int s = 0;
    for (int i = start; i < end; ++i) s += in[i];
    sums[t] = s;
    __syncthreads();
    if (t == 0) {
        int acc = 0;
        for (int i = 0; i < 1024; ++i) { int v = sums[i]; sums[i] = acc; acc += v; }
        out[n] = acc;
    }
    __syncthreads();
    int acc = sums[t];
    for (int i = start; i < end; ++i) { out[i] = acc; acc += in[i]; }
}

__global__ void fill_self_kernel(int* __restrict__ pos, int* __restrict__ srcl, int n) {
    int i = blockIdx.x * blockDim.x + threadIdx.x;
    if (i < n) { int slot = atomicAdd(&pos[i], 1); srcl[slot] = i; }
}

__global__ void fill_edge_kernel(const int* __restrict__ src, const int* __restrict__ dst, int e,
                                 int* __restrict__ pos, int* __restrict__ srcl) {
    int i = blockIdx.x * blockDim.x + threadIdx.x;
    if (i < e) { int slot = atomicAdd(&pos[dst[i]], 1); srcl[slot] = src[i]; }
}

__global__ void f32_to_bf16(const float* __restrict__ in, u16* __restrict__ out, int n) {
    int i = blockIdx.x * blockDim.x + threadIdx.x;
    if (i < n) out[i] = f2bf(in[i]);
}

// ---------------- embedding mean -> bf16 ----------------

__global__ void embed_mean_kernel(const int* __restrict__ drug_x, const float* __restrict__ emb,
                                  u16* __restrict__ out) {
    const int n = blockIdx.x;
    __shared__ int idx[9];
    if (threadIdx.x < 9) idx[threadIdx.x] = drug_x[n * 9 + threadIdx.x];
    __syncthreads();
    const int c = threadIdx.x;  // blockDim == C_MOL == 512
    float s = 0.f;
#pragma unroll
    for (int t = 0; t < 9; ++t) s += emb[(size_t)idx[t] * C_MOL + c];
    out[(size_t)n * C_MOL + c] = f2bf(s * (1.f / 9.f));
}

// ---------------- fold attention vectors: wsrc[h][i] = sum_c W[i][h*COUT+c]*asrc[h][c] ----------------

template <int CIN, int COUT>
__global__ __launch_bounds__(256) void fold_attn(const float* __restrict__ W,
                                                 const float* __restrict__ asrc,
                                                 const float* __restrict__ adst,
                                                 float* __restrict__ wsrc, float* __restrict__ wdst) {
    const int i = blockIdx.x;  // grid = CIN
    const int tid = threadIdx.x;
    __shared__ float rb[8];
    const float* Wr = W + (size_t)i * (H_HEADS * COUT);
    for (int h = 0; h < H_HEADS; ++h) {
        float ss = 0.f, sd = 0.f;
        for (int c = tid; c < COUT; c += 256) {
            const float w = Wr[h * COUT + c];
            ss += w * asrc[h * COUT + c];
            sd += w * adst[h * COUT + c];
        }
        for (int o = 32; o; o >>= 1) { ss += __shfl_down(ss, o); sd += __shfl_down(sd, o); }
        if ((tid & 63) == 0) { rb[tid >> 6] = ss; rb[4 + (tid >> 6)] = sd; }
        __syncthreads();
        if (tid == 0) {
            wsrc[h * CIN + i] = rb[0] + rb[1] + rb[2] + rb[3];
            wdst[h * CIN + i] = rb[4] + rb[5] + rb[6] + rb[7];
        }
        __syncthreads();
    }
}

// ---------------- weight transpose+convert: Wt[h][n][k] = bf16(W[k][h*COUT+n]) ----------------

template <int CIN, int COUT>
__global__ __launch_bounds__(256) void transposeW(const float* __restrict__ W, u16* __restrict__ Wt) {
    __shared__ float t[32][33];
    const int h = blockIdx.z;
    const int n0 = blockIdx.x * 32, k0 = blockIdx.y * 32;
    const int tx = threadIdx.x & 31, ty = threadIdx.x >> 5;  // 32x8
#pragma unroll
    for (int q = 0; q < 4; ++q)
        t[ty + q * 8][tx] = W[(size_t)(k0 + ty + q * 8) * (H_HEADS * COUT) + h * COUT + n0 + tx];
    __syncthreads();
#pragma unroll
    for (int q = 0; q < 4; ++q)
        Wt[(size_t)h * COUT * CIN + (size_t)(n0 + ty + q * 8) * CIN + k0 + tx] = f2bf(t[tx][ty + q * 8]);
}

// ---------------- attention logits from x (folded): one wave per node ----------------

template <int C>
__global__ void attn_logits(const u16* __restrict__ x, const float* __restrict__ wsrc,
                            const float* __restrict__ wdst, float* __restrict__ als,
                            float* __restrict__ ald) {
    const int n = blockIdx.x, lane = threadIdx.x;  // blockDim == 64
    const u16* xr = x + (size_t)n * C;
    float xv[C / 64];
#pragma unroll
    for (int i = 0; i < C / 64; ++i) xv[i] = bf2f(xr[i * 64 + lane]);
    for (int h = 0; h < H_HEADS; ++h) {
        float ss = 0.f, sd = 0.f;
#pragma unroll
        for (int i = 0; i < C / 64; ++i) {
            ss += xv[i] * wsrc[h * C + i * 64 + lane];
            sd += xv[i] * wdst[h * C + i * 64 + lane];
        }
        for (int o = 32; o; o >>= 1) { ss += __shfl_down(ss, o); sd += __shfl_down(sd, o); }
        if (lane == 0) { als[n * H_HEADS + h] = ss; ald[n * H_HEADS + h] = sd; }
    }
}

// ---------------- segment softmax -> alpha per CSR slot ----------------

__global__ void alpha_kernel(const float* __restrict__ als, const float* __restrict__ ald,
                             const int* __restrict__ indptr, const int* __restrict__ srcl,
                             float* __restrict__ alphaw) {
    const int n = blockIdx.x, lane = threadIdx.x;  // blockDim == 64, lanes 0..2 active
    if (lane >= H_HEADS) return;
    const int beg = indptr[n], end = indptr[n + 1];
    const float ad = ald[n * H_HEADS + lane];
    float m = -1e30f;
    for (int e = beg; e < end; ++e) {
        float v = als[srcl[e] * H_HEADS + lane] + ad;
        v = v >= 0.f ? v : NEG_SLOPE * v;
        m = fmaxf(m, v);
    }
    float z = 0.f;
    for (int e = beg; e < end; ++e) {
        float v = als[srcl[e] * H_HEADS + lane] + ad;
        v = v >= 0.f ? v : NEG_SLOPE * v;
        z += __expf(v - m);
    }
    const float zi = 1.f / (z + 1e-16f);
    for (int e = beg; e < end; ++e) {
        float v = als[srcl[e] * H_HEADS + lane] + ad;
        v = v >= 0.f ? v : NEG_SLOPE * v;
        alphaw[e * H_HEADS + lane] = __expf(v - m) * zi;
    }
}

// ---------------- per-head weighted aggregation of x (bf16 in/out) ----------------

template <int C>
__global__ __launch_bounds__(256) void aggregate_head(const u16* __restrict__ x,
                                                      const float* __restrict__ alphaw,
                                                      const int* __restrict__ indptr,
                                                      const int* __restrict__ srcl, int head,
                                                      u16* __restrict__ aggH) {
    constexpr int PER = C / 256;
    const int n = blockIdx.x, tid = threadIdx.x;
    const int beg = indptr[n], end = indptr[n + 1];
    float vals[PER];
#pragma unroll
    for (int i = 0; i < PER; ++i) vals[i] = 0.f;
    for (int e = beg; e < end; ++e) {
        const float a = alphaw[e * H_HEADS + head];
        const u16* xs = x + (size_t)srcl[e] * C;
#pragma unroll
        for (int i = 0; i < PER; ++i) vals[i] += a * bf2f(xs[i * 256 + tid]);
    }
    u16* o = aggH + (size_t)n * C;
#pragma unroll
    for (int i = 0; i < PER; ++i) o[i * 256 + tid] = f2bf(vals[i]);
}

// ---------------- bf16 MFMA GEMM: C[M,N] (+)= A[M,K] @ Bt[N,K]^T ----------------
// BM=64, BN=256, BK=32, 256 threads = 4 waves; wave w owns cols [w*64, w*64+64).
// mfma_f32_16x16x32_bf16: A lane l: row=l&15, k=8*(l>>4)+j; B lane l: col=l&15, same k;
// D lane l reg r: row=(l>>4)*4+r, col=l&15  [m89-verified].

template <int BETA>
__global__ __launch_bounds__(256) void gemm_mfma(const u16* __restrict__ A,
                                                 const u16* __restrict__ Bt,
                                                 u16* __restrict__ C, int M, int N, int K) {
    __shared__ u16 As[64][40];    // 32 K-cols + 8 pad
    __shared__ u16 Bs[256][40];
    const int tid = threadIdx.x;
    const int w = tid >> 6;
    const int l = tid & 63;
    const int bm = blockIdx.y * 64;
    const int bn = blockIdx.x * 256;
    const f32x4 zf = {0.f, 0.f, 0.f, 0.f};
    f32x4 acc[4][4];
#pragma unroll
    for (int i = 0; i < 4; ++i)
#pragma unroll
        for (int j = 0; j < 4; ++j) acc[i][j] = zf;

    const int arow = tid >> 2, aseg = tid & 3;
    const u16* Ab = A + (size_t)(bm + arow) * K + aseg * 8;
    for (int k0 = 0; k0 < K; k0 += 32) {
        const float4 av = *(const float4*)(Ab + k0);
        float4 bv[4];
#pragma unroll
        for (int q = 0; q < 4; ++q) {
            const int c = q * 256 + tid;
            bv[q] = *(const float4*)(Bt + (size_t)(bn + (c >> 2)) * K + k0 + (c & 3) * 8);
        }
        __syncthreads();
        *(float4*)&As[arow][aseg * 8] = av;
#pragma unroll
        for (int q = 0; q < 4; ++q) {
            const int c = q * 256 + tid;
            *(float4*)&Bs[c >> 2][(c & 3) * 8] = bv[q];
        }
        __syncthreads();
        const int koff = 8 * (l >> 4);
        const int rl = l & 15;
        short8v af[4], bfr[4];
#pragma unroll
        for (int fm = 0; fm < 4; ++fm) af[fm] = *(const short8v*)&As[fm * 16 + rl][koff];
#pragma unroll
        for (int fn = 0; fn < 4; ++fn) bfr[fn] = *(const short8v*)&Bs[w * 64 + fn * 16 + rl][koff];
#pragma unroll
        for (int fm = 0; fm < 4; ++fm)
#pragma unroll
            for (int fn = 0; fn < 4; ++fn)
                acc[fm][fn] =
                    __builtin_amdgcn_mfma_f32_16x16x32_bf16(af[fm], bfr[fn], acc[fm][fn], 0, 0, 0);
    }
    const int r0 = (l >> 4) * 4;
    const int cn = l & 15;
#pragma unroll
    for (int fm = 0; fm < 4; ++fm)
#pragma unroll
        for (int fn = 0; fn < 4; ++fn) {
            u16* Cp = C + (size_t)(bm + fm * 16 + r0) * N + bn + w * 64 + fn * 16 + cn;
#pragma unroll
            for (int r = 0; r < 4; ++r) {
                float v = acc[fm][fn][r];
                if (BETA) v += bf2f(Cp[(size_t)r * N]);
                Cp[(size_t)r * N] = f2bf(v);
            }
        }
}

// ---------------- fused scale + bias + LayerNorm -> next-layer x (bf16) ----------------

template <int C>
__global__ __launch_bounds__(256) void ln_kernel(const u16* __restrict__ acc,
                                                 const float* __restrict__ bias,
                                                 const float* __restrict__ g,
                                                 const float* __restrict__ b,
                                                 u16* __restrict__ xout) {
    constexpr int PER = C / 256;
    const int n = blockIdx.x, tid = threadIdx.x;
    const u16* ar = acc + (size_t)n * C;
    float vals[PER];
    float s1 = 0.f, s2 = 0.f;
    constexpr float invH = 1.f / (float)H_HEADS;
#pragma unroll
    for (int i = 0; i < PER; ++i) {
        const int c = i * 256 + tid;
        const float v = bf2f(ar[c]) * invH + bias[c];
        vals[i] = v;
        s1 += v;
        s2 += v * v;
    }
    __shared__ float red[2][4];
    for (int o = 32; o; o >>= 1) { s1 += __shfl_down(s1, o); s2 += __shfl_down(s2, o); }
    if ((tid & 63) == 0) { red[0][tid >> 6] = s1; red[1][tid >> 6] = s2; }
    __syncthreads();
    const float t1 = red[0][0] + red[0][1] + red[0][2] + red[0][3];
    const float t2 = red[1][0] + red[1][1] + red[1][2] + red[1][3];
    const float mu = t1 / C;
    const float var = t2 / C - mu * mu;
    const float rstd = rsqrtf(var + LN_EPS);
    u16* xr = xout + (size_t)n * C;
#pragma unroll
    for (int i = 0; i < PER; ++i) {
        const int c = i * 256 + tid;
        xr[c] = f2bf((vals[i] - mu) * rstd * g[c] + b[c]);
    }
}

// ---------------- mean pool (bf16 input, f32 output) ----------------

template <int C>
__global__ void pool_bf16(const u16* __restrict__ x, const int* __restrict__ goff,
                          float* __restrict__ out, int layer) {
    const int gidx = blockIdx.x;
    const int beg = goff[gidx], end = goff[gidx + 1];
    const float inv = 1.f / fmaxf((float)(end - beg), 1.f);
    for (int c = threadIdx.x; c < C; c += blockDim.x) {
        float s = 0.f;
        for (int n = beg; n < end; ++n) s += bf2f(x[(size_t)n * C + c]);
        out[((size_t)gidx * (LAYERS + 1) + layer) * C + c] = s * inv;
    }
}

// ---------------- launch ----------------

extern "C" void kernel_launch(void* const* d_in, const int* in_sizes, int n_in, void* d_out,
                              int out_size, void* d_ws, size_t ws_size, hipStream_t stream) {
    const int* drug_x      = (const int*)d_in[0];
    const int* mol_ei      = (const int*)d_in[1];
    const int* mol_batch   = (const int*)d_in[2];
    const float* prot_in   = (const float*)d_in[3];
    const int* prot_ei     = (const int*)d_in[4];
    const int* prot_batch  = (const int*)d_in[5];
    const float* emb       = (const float*)d_in[6];
    const float* mol_W     = (const float*)d_in[7];
    const float* mol_asrc  = (const float*)d_in[8];
    const float* mol_adst  = (const float*)d_in[9];
    const float* mol_bias  = (const float*)d_in[10];
    const float* mol_lng   = (const float*)d_in[11];
    const float* mol_lnb   = (const float*)d_in[12];
    const float* prot_W    = (const float*)d_in[13];
    const float* prot_asrc = (const float*)d_in[14];
    const float* prot_adst = (const float*)d_in[15];
    const float* prot_bias = (const float*)d_in[16];
    const float* prot_lng  = (const float*)d_in[17];
    const float* prot_lnb  = (const float*)d_in[18];

    // Diagnostic guard: exact need is ~156.94 MB. If ws is smaller, no-op
    // (bench then fails with absmax ~0.9 instead of crashing -> tells us ws_size).
    if (ws_size < (size_t)157000000) return;

    char* base = (char*)d_ws;
    size_t off = 0;
    auto alloc = [&](size_t bytes) -> void* {
        void* r = base + off;
        off = (off + bytes + 255) & ~(size_t)255;
        return r;
    };
    u16* x_mol  = (u16*)alloc((size_t)N_MOL * C_MOL * 2);                 // 40.96 MB
    u16* x_prot = (u16*)alloc((size_t)N_PROT * C_PROT * 2);               // 20.48 MB
    u16* aggH   = (u16*)alloc((size_t)N_MOL * C_MOL * 2);                 // 40.96 MB (shared)
    u16* outb   = (u16*)alloc((size_t)N_MOL * C_MOL * 2);                 // 40.96 MB (shared)
    u16* Wt     = (u16*)alloc((size_t)H_HEADS * C_PROT * C_PROT * 2);     // 9.83 MB
    float* wsrc = (float*)alloc((size_t)H_HEADS * C_PROT * 4);
    float* wdst = (float*)alloc((size_t)H_HEADS * C_PROT * 4);
    float* als  = (float*)alloc((size_t)N_MOL * H_HEADS * 4);
    float* ald  = (float*)alloc((size_t)N_MOL * H_HEADS * 4);
    float* alphaw = (float*)alloc((size_t)(E_MOL + N_MOL) * H_HEADS * 4); // 1.44 MB
    int* mol_indptr  = (int*)alloc((N_MOL + 1) * 4);
    int* mol_pos     = (int*)alloc(N_MOL * 4);
    int* mol_srcl    = (int*)alloc((E_MOL + N_MOL) * 4);
    int* prot_indptr = (int*)alloc((N_PROT + 1) * 4);
    int* prot_pos    = (int*)alloc(N_PROT * 4);
    int* prot_srcl   = (int*)alloc((E_PROT + N_PROT) * 4);
    int* cnt         = (int*)alloc(N_MOL * 4);
    int* mol_goff    = (int*)alloc((G_MOL + 1) * 4);
    int* prot_goff   = (int*)alloc((G_PROT + 1) * 4);
    int* gcnt        = (int*)alloc(G_MOL * 4);

    float* out_mol  = (float*)d_out;
    float* out_prot = (float*)d_out + (size_t)G_MOL * (LAYERS + 1) * C_MOL;

    // ---- CSR (incoming lists incl. self loops) ----
    set_int_kernel<<<(N_MOL + 255) / 256, 256, 0, stream>>>(cnt, 1, N_MOL);
    hist_kernel<<<(E_MOL + 255) / 256, 256, 0, stream>>>(mol_ei + E_MOL, E_MOL, cnt);
    scan_kernel<<<1, 1024, 0, stream>>>(cnt, mol_indptr, N_MOL);
    copy_int_kernel<<<(N_MOL + 255) / 256, 256, 0, stream>>>(mol_indptr, mol_pos, N_MOL);
    fill_self_kernel<<<(N_MOL + 255) / 256, 256, 0, stream>>>(mol_pos, mol_srcl, N_MOL);
    fill_edge_kernel<<<(E_MOL + 255) / 256, 256, 0, stream>>>(mol_ei, mol_ei + E_MOL, E_MOL, mol_pos,
                                                              mol_srcl);

    set_int_kernel<<<(N_PROT + 255) / 256, 256, 0, stream>>>(cnt, 1, N_PROT);
    hist_kernel<<<(E_PROT + 255) / 256, 256, 0, stream>>>(prot_ei + E_PROT, E_PROT, cnt);
    scan_kernel<<<1, 1024, 0, stream>>>(cnt, prot_indptr, N_PROT);
    copy_int_kernel<<<(N_PROT + 255) / 256, 256, 0, stream>>>(prot_indptr, prot_pos, N_PROT);
    fill_self_kernel<<<(N_PROT + 255) / 256, 256, 0, stream>>>(prot_pos, prot_srcl, N_PROT);
    fill_edge_kernel<<<(E_PROT + 255) / 256, 256, 0, stream>>>(prot_ei, prot_ei + E_PROT, E_PROT,
                                                               prot_pos, prot_srcl);

    // ---- graph offsets for pooling (batch sorted) ----
    set_int_kernel<<<(G_MOL + 255) / 256, 256, 0, stream>>>(gcnt, 0, G_MOL);
    hist_kernel<<<(N_MOL + 255) / 256, 256, 0, stream>>>(mol_batch, N_MOL, gcnt);
    scan_kernel<<<1, 1024, 0, stream>>>(gcnt, mol_goff, G_MOL);
    set_int_kernel<<<(G_PROT + 255) / 256, 256, 0, stream>>>(gcnt, 0, G_PROT);
    hist_kernel<<<(N_PROT + 255) / 256, 256, 0, stream>>>(prot_batch, N_PROT, gcnt);
    scan_kernel<<<1, 1024, 0, stream>>>(gcnt, prot_goff, G_PROT);

    // ---- layer-0 features ----
    f32_to_bf16<<<(N_PROT * C_PROT + 255) / 256, 256, 0, stream>>>(prot_in, x_prot, N_PROT * C_PROT);
    embed_mean_kernel<<<N_MOL, C_MOL, 0, stream>>>(drug_x, emb, x_mol);
    pool_bf16<C_MOL><<<G_MOL, 256, 0, stream>>>(x_mol, mol_goff, out_mol, 0);
    pool_bf16<C_PROT><<<G_PROT, 256, 0, stream>>>(x_prot, prot_goff, out_prot, 0);

    for (int l = 0; l < LAYERS; ++l) {
        // ---- molecule branch ----
        {
            const float* Wl = mol_W + (size_t)l * C_MOL * (H_HEADS * C_MOL);
            fold_attn<C_MOL, C_MOL><<<C_MOL, 256, 0, stream>>>(
                Wl, mol_asrc + (size_t)l * H_HEADS * C_MOL, mol_adst + (size_t)l * H_HEADS * C_MOL,
                wsrc, wdst);
            transposeW<C_MOL, C_MOL><<<dim3(C_MOL / 32, C_MOL / 32, H_HEADS), 256, 0, stream>>>(Wl, Wt);
            attn_logits<C_MOL><<<N_MOL, 64, 0, stream>>>(x_mol, wsrc, wdst, als, ald);
            alpha_kernel<<<N_MOL, 64, 0, stream>>>(als, ald, mol_indptr, mol_srcl, alphaw);
            for (int h = 0; h < H_HEADS; ++h) {
                aggregate_head<C_MOL><<<N_MOL, 256, 0, stream>>>(x_mol, alphaw, mol_indptr, mol_srcl,
                                                                 h, aggH);
                const u16* Bh = Wt + (size_t)h * C_MOL * C_MOL;
                if (h == 0)
                    gemm_mfma<0><<<dim3(C_MOL / 256, N_MOL / 64), 256, 0, stream>>>(
                        aggH, Bh, outb, N_MOL, C_MOL, C_MOL);
                else
                    gemm_mfma<1><<<dim3(C_MOL / 256, N_MOL / 64), 256, 0, stream>>>(
                        aggH, Bh, outb, N_MOL, C_MOL, C_MOL);
            }
            ln_kernel<C_MOL><<<N_MOL, 256, 0, stream>>>(outb, mol_bias + (size_t)l * C_MOL,
                                                        mol_lng + (size_t)l * C_MOL,
                                                        mol_lnb + (size_t)l * C_MOL, x_mol);
            pool_bf16<C_MOL><<<G_MOL, 256, 0, stream>>>(x_mol, mol_goff, out_mol, l + 1);
        }
        // ---- protein branch ----
        {
            const float* Wl = prot_W + (size_t)l * C_PROT * (H_HEADS * C_PROT);
            fold_attn<C_PROT, C_PROT><<<C_PROT, 256, 0, stream>>>(
                Wl, prot_asrc + (size_t)l * H_HEADS * C_PROT,
                prot_adst + (size_t)l * H_HEADS * C_PROT, wsrc, wdst);
            transposeW<C_PROT, C_PROT><<<dim3(C_PROT / 32, C_PROT / 32, H_HEADS), 256, 0, stream>>>(
                Wl, Wt);
            attn_logits<C_PROT><<<N_PROT, 64, 0, stream>>>(x_prot, wsrc, wdst, als, ald);
            alpha_kernel<<<N_PROT, 64, 0, stream>>>(als, ald, prot_indptr, prot_srcl, alphaw);
            for (int h = 0; h < H_HEADS; ++h) {
                aggregate_head<C_PROT><<<N_PROT, 256, 0, stream>>>(x_prot, alphaw, prot_indptr,
                                                                   prot_srcl, h, aggH);
                const u16* Bh = Wt + (size_t)h * C_PROT * C_PROT;
                if (h == 0)
                    gemm_mfma<0><<<dim3(C_PROT / 256, N_PROT / 64), 256, 0, stream>>>(
                        aggH, Bh, outb, N_PROT, C_PROT, C_PROT);
                else
                    gemm_mfma<1><<<dim3(C_PROT / 256, N_PROT / 64), 256, 0, stream>>>(
                        aggH, Bh, outb, N_PROT, C_PROT, C_PROT);
            }
            ln_kernel<C_PROT><<<N_PROT, 256, 0, stream>>>(outb, prot_bias + (size_t)l * C_PROT,
                                                          prot_lng + (size_t)l * C_PROT,
                                                          prot_lnb + (size_t)l * C_PROT, x_prot);
            pool_bf16<C_PROT><<<G_PROT, 256, 0, stream>>>(x_prot, prot_goff, out_prot, l + 1);
        }
    }
}

// Round 3
// 5367.366 us; speedup vs baseline: 1.2979x; 1.2979x over previous
//
#include <hip/hip_runtime.h>
#include <cstdint>

// R3: fix pool (1.25% occupancy, 340us each -> parallel segmented atomic pool),
// vectorize aggregate_head + attn_logits (short4 loads). Structure unchanged.

constexpr int H_HEADS = 3;
constexpr float NEG_SLOPE = 0.2f;
constexpr float LN_EPS = 1e-5f;
constexpr int N_MOL = 40000, E_MOL = 80000, C_MOL = 512, G_MOL = 512;
constexpr int N_PROT = 8000, E_PROT = 64000, C_PROT = 1280, G_PROT = 32;
constexpr int LAYERS = 4;

typedef unsigned short u16;
typedef __attribute__((ext_vector_type(8))) short short8v;
typedef __attribute__((ext_vector_type(4))) unsigned short ushort4v;
typedef __attribute__((ext_vector_type(4))) float f32x4;

__device__ __forceinline__ float bf2f(u16 s) {
    union { unsigned u; float f; } v; v.u = ((unsigned)s) << 16; return v.f;
}
__device__ __forceinline__ u16 f2bf(float f) {
    union { float f; unsigned u; } v; v.f = f;
    return (u16)((v.u + 0x7fffu + ((v.u >> 16) & 1u)) >> 16);
}

// ---------------- small utility kernels ----------------

__global__ void set_int_kernel(int* p, int v, int n) {
    int i = blockIdx.x * blockDim.x + threadIdx.x;
    if (i < n) p[i] = v;
}

__global__ void zero_f32_kernel(float* p, int n) {
    int i = blockIdx.x * blockDim.x + threadIdx.x;
    if (i < n) p[i] = 0.f;
}

__global__ void copy_int_kernel(const int* __restrict__ s, int* __restrict__ d, int n) {
    int i = blockIdx.x * blockDim.x + threadIdx.x;
    if (i < n) d[i] = s[i];
}

__global__ void hist_kernel(const int* __restrict__ keys, int n, int* __restrict__ cnt) {
    int i = blockIdx.x * blockDim.x + threadIdx.x;
    if (i < n) atomicAdd(&cnt[keys[i]], 1);
}

// single-block exclusive scan; out has n+1 entries (out[n] = total)
__global__ void scan_kernel(const int* __restrict__ in, int* __restrict__ out, int n) {
    __shared__ int sums[1024];
    const int t = threadIdx.x;
    const int chunk = (n + 1023) / 1024;
    const int start = t * chunk;
    const int end = min(start + chunk, n);
    int s = 0;
    for (int i = start; i < end; ++i) s += in[i];
    sums[t] = s;
    __syncthreads();
    if (t == 0) {
        int acc = 0;
        for (int i = 0; i < 1024; ++i) { int v = sums[i]; sums[i] = acc; acc += v; }
        out[n] = acc;
    }
    __syncthreads();
    int acc = sums[t];
    for (int i = start; i < end; ++i) { out[i] = acc; acc += in[i]; }
}

__global__ void fill_self_kernel(int* __restrict__ pos, int* __restrict__ srcl, int n) {
    int i = blockIdx.x * blockDim.x + threadIdx.x;
    if (i < n) { int slot = atomicAdd(&pos[i], 1); srcl[slot] = i; }
}

__global__ void fill_edge_kernel(const int* __restrict__ src, const int* __restrict__ dst, int e,
                                 int* __restrict__ pos, int* __restrict__ srcl) {
    int i = blockIdx.x * blockDim.x + threadIdx.x;
    if (i < e) { int slot = atomicAdd(&pos[dst[i]], 1); srcl[slot] = src[i]; }
}

__global__ void f32_to_bf16(const float* __restrict__ in, u16* __restrict__ out, int n) {
    int i = blockIdx.x * blockDim.x + threadIdx.x;
    if (i < n) out[i] = f2bf(in[i]);
}

// ---------------- embedding mean -> bf16 ----------------

__global__ void embed_mean_kernel(const int* __restrict__ drug_x, const float* __restrict__ emb,
                                  u16* __restrict__ out) {
    const int n = blockIdx.x;
    __shared__ int idx[9];
    if (threadIdx.x < 9) idx[threadIdx.x] = drug_x[n * 9 + threadIdx.x];
    __syncthreads();
    const int c = threadIdx.x;  // blockDim == C_MOL == 512
    float s = 0.f;
#pragma unroll
    for (int t = 0; t < 9; ++t) s += emb[(size_t)idx[t] * C_MOL + c];
    out[(size_t)n * C_MOL + c] = f2bf(s * (1.f / 9.f));
}

// ---------------- fold attention vectors: wsrc[h][i] = sum_c W[i][h*COUT+c]*asrc[h][c] ----------------

template <int CIN, int COUT>
__global__ __launch_bounds__(256) void fold_attn(const float* __restrict__ W,
                                                 const float* __restrict__ asrc,
                                                 const float* __restrict__ adst,
                                                 float* __restrict__ wsrc, float* __restrict__ wdst) {
    const int i = blockIdx.x;  // grid = CIN
    const int tid = threadIdx.x;
    __shared__ float rb[8];
    const float* Wr = W + (size_t)i * (H_HEADS * COUT);
    for (int h = 0; h < H_HEADS; ++h) {
        float ss = 0.f, sd = 0.f;
        for (int c = tid; c < COUT; c += 256) {
            const float w = Wr[h * COUT + c];
            ss += w * asrc[h * COUT + c];
            sd += w * adst[h * COUT + c];
        }
        for (int o = 32; o; o >>= 1) { ss += __shfl_down(ss, o); sd += __shfl_down(sd, o); }
        if ((tid & 63) == 0) { rb[tid >> 6] = ss; rb[4 + (tid >> 6)] = sd; }
        __syncthreads();
        if (tid == 0) {
            wsrc[h * CIN + i] = rb[0] + rb[1] + rb[2] + rb[3];
            wdst[h * CIN + i] = rb[4] + rb[5] + rb[6] + rb[7];
        }
        __syncthreads();
    }
}

// ---------------- weight transpose+convert: Wt[h][n][k] = bf16(W[k][h*COUT+n]) ----------------

template <int CIN, int COUT>
__global__ __launch_bounds__(256) void transposeW(const float* __restrict__ W, u16* __restrict__ Wt) {
    __shared__ float t[32][33];
    const int h = blockIdx.z;
    const int n0 = blockIdx.x * 32, k0 = blockIdx.y * 32;
    const int tx = threadIdx.x & 31, ty = threadIdx.x >> 5;  // 32x8
#pragma unroll
    for (int q = 0; q < 4; ++q)
        t[ty + q * 8][tx] = W[(size_t)(k0 + ty + q * 8) * (H_HEADS * COUT) + h * COUT + n0 + tx];
    __syncthreads();
#pragma unroll
    for (int q = 0; q < 4; ++q)
        Wt[(size_t)h * COUT * CIN + (size_t)(n0 + ty + q * 8) * CIN + k0 + tx] = f2bf(t[tx][ty + q * 8]);
}

// ---------------- attention logits from x (folded): one wave per node, vectorized ----------------

template <int C>
__global__ void attn_logits(const u16* __restrict__ x, const float* __restrict__ wsrc,
                            const float* __restrict__ wdst, float* __restrict__ als,
                            float* __restrict__ ald) {
    constexpr int PER = C / 64;  // 8 (mol) / 20 (prot), both %4==0
    const int n = blockIdx.x, lane = threadIdx.x;  // blockDim == 64
    const u16* xr = x + (size_t)n * C + lane * PER;
    float xv[PER];
#pragma unroll
    for (int i = 0; i < PER; i += 4) {
        const ushort4v v = *(const ushort4v*)(xr + i);
        xv[i] = bf2f(v.x); xv[i + 1] = bf2f(v.y); xv[i + 2] = bf2f(v.z); xv[i + 3] = bf2f(v.w);
    }
    for (int h = 0; h < H_HEADS; ++h) {
        const float* ws = wsrc + h * C + lane * PER;
        const float* wd = wdst + h * C + lane * PER;
        float ss = 0.f, sd = 0.f;
#pragma unroll
        for (int i = 0; i < PER; i += 4) {
            const float4 a = *(const float4*)(ws + i);
            const float4 b = *(const float4*)(wd + i);
            ss += xv[i] * a.x + xv[i + 1] * a.y + xv[i + 2] * a.z + xv[i + 3] * a.w;
            sd += xv[i] * b.x + xv[i + 1] * b.y + xv[i + 2] * b.z + xv[i + 3] * b.w;
        }
        for (int o = 32; o; o >>= 1) { ss += __shfl_down(ss, o); sd += __shfl_down(sd, o); }
        if (lane == 0) { als[n * H_HEADS + h] = ss; ald[n * H_HEADS + h] = sd; }
    }
}

// ---------------- segment softmax -> alpha per CSR slot ----------------

__global__ void alpha_kernel(const float* __restrict__ als, const float* __restrict__ ald,
                             const int* __restrict__ indptr, const int* __restrict__ srcl,
                             float* __restrict__ alphaw) {
    const int n = blockIdx.x, lane = threadIdx.x;  // blockDim == 64, lanes 0..2 active
    if (lane >= H_HEADS) return;
    const int beg = indptr[n], end = indptr[n + 1];
    const float ad = ald[n * H_HEADS + lane];
    float m = -1e30f;
    for (int e = beg; e < end; ++e) {
        float v = als[srcl[e] * H_HEADS + lane] + ad;
        v = v >= 0.f ? v : NEG_SLOPE * v;
        m = fmaxf(m, v);
    }
    float z = 0.f;
    for (int e = beg; e < end; ++e) {
        float v = als[srcl[e] * H_HEADS + lane] + ad;
        v = v >= 0.f ? v : NEG_SLOPE * v;
        z += __expf(v - m);
    }
    const float zi = 1.f / (z + 1e-16f);
    for (int e = beg; e < end; ++e) {
        float v = als[srcl[e] * H_HEADS + lane] + ad;
        v = v >= 0.f ? v : NEG_SLOPE * v;
        alphaw[e * H_HEADS + lane] = __expf(v - m) * zi;
    }
}

// ---------------- per-head weighted aggregation of x (bf16 in/out), vectorized ----------------
// block = C/4 threads (mol 128, prot 320); each thread owns 4 contiguous channels.

template <int C>
__global__ void aggregate_head(const u16* __restrict__ x, const float* __restrict__ alphaw,
                               const int* __restrict__ indptr, const int* __restrict__ srcl,
                               int head, u16* __restrict__ aggH) {
    const int n = blockIdx.x, tid = threadIdx.x;
    const int beg = indptr[n], end = indptr[n + 1];
    float a0 = 0.f, a1 = 0.f, a2 = 0.f, a3 = 0.f;
    for (int e = beg; e < end; ++e) {
        const float a = alphaw[e * H_HEADS + head];
        const ushort4v v = *(const ushort4v*)(x + (size_t)srcl[e] * C + tid * 4);
        a0 += a * bf2f(v.x); a1 += a * bf2f(v.y); a2 += a * bf2f(v.z); a3 += a * bf2f(v.w);
    }
    ushort4v r;
    r.x = f2bf(a0); r.y = f2bf(a1); r.z = f2bf(a2); r.w = f2bf(a3);
    *(ushort4v*)(aggH + (size_t)n * C + tid * 4) = r;
}

// ---------------- bf16 MFMA GEMM: C[M,N] (+)= A[M,K] @ Bt[N,K]^T ----------------
// BM=64, BN=256, BK=32, 256 threads = 4 waves; wave w owns cols [w*64, w*64+64).

template <int BETA>
__global__ __launch_bounds__(256) void gemm_mfma(const u16* __restrict__ A,
                                                 const u16* __restrict__ Bt,
                                                 u16* __restrict__ C, int M, int N, int K) {
    __shared__ u16 As[64][40];    // 32 K-cols + 8 pad
    __shared__ u16 Bs[256][40];
    const int tid = threadIdx.x;
    const int w = tid >> 6;
    const int l = tid & 63;
    const int bm = blockIdx.y * 64;
    const int bn = blockIdx.x * 256;
    const f32x4 zf = {0.f, 0.f, 0.f, 0.f};
    f32x4 acc[4][4];
#pragma unroll
    for (int i = 0; i < 4; ++i)
#pragma unroll
        for (int j = 0; j < 4; ++j) acc[i][j] = zf;

    const int arow = tid >> 2, aseg = tid & 3;
    const u16* Ab = A + (size_t)(bm + arow) * K + aseg * 8;
    for (int k0 = 0; k0 < K; k0 += 32) {
        const float4 av = *(const float4*)(Ab + k0);
        float4 bv[4];
#pragma unroll
        for (int q = 0; q < 4; ++q) {
            const int c = q * 256 + tid;
            bv[q] = *(const float4*)(Bt + (size_t)(bn + (c >> 2)) * K + k0 + (c & 3) * 8);
        }
        __syncthreads();
        *(float4*)&As[arow][aseg * 8] = av;
#pragma unroll
        for (int q = 0; q < 4; ++q) {
            const int c = q * 256 + tid;
            *(float4*)&Bs[c >> 2][(c & 3) * 8] = bv[q];
        }
        __syncthreads();
        const int koff = 8 * (l >> 4);
        const int rl = l & 15;
        short8v af[4], bfr[4];
#pragma unroll
        for (int fm = 0; fm < 4; ++fm) af[fm] = *(const short8v*)&As[fm * 16 + rl][koff];
#pragma unroll
        for (int fn = 0; fn < 4; ++fn) bfr[fn] = *(const short8v*)&Bs[w * 64 + fn * 16 + rl][koff];
#pragma unroll
        for (int fm = 0; fm < 4; ++fm)
#pragma unroll
            for (int fn = 0; fn < 4; ++fn)
                acc[fm][fn] =
                    __builtin_amdgcn_mfma_f32_16x16x32_bf16(af[fm], bfr[fn], acc[fm][fn], 0, 0, 0);
    }
    const int r0 = (l >> 4) * 4;
    const int cn = l & 15;
#pragma unroll
    for (int fm = 0; fm < 4; ++fm)
#pragma unroll
        for (int fn = 0; fn < 4; ++fn) {
            u16* Cp = C + (size_t)(bm + fm * 16 + r0) * N + bn + w * 64 + fn * 16 + cn;
#pragma unroll
            for (int r = 0; r < 4; ++r) {
                float v = acc[fm][fn][r];
                if (BETA) v += bf2f(Cp[(size_t)r * N]);
                Cp[(size_t)r * N] = f2bf(v);
            }
        }
}

// ---------------- fused scale + bias + LayerNorm -> next-layer x (bf16) ----------------

template <int C>
__global__ __launch_bounds__(256) void ln_kernel(const u16* __restrict__ acc,
                                                 const float* __restrict__ bias,
                                                 const float* __restrict__ g,
                                                 const float* __restrict__ b,
                                                 u16* __restrict__ xout) {
    constexpr int PER = C / 256;
    const int n = blockIdx.x, tid = threadIdx.x;
    const u16* ar = acc + (size_t)n * C;
    float vals[PER];
    float s1 = 0.f, s2 = 0.f;
    constexpr float invH = 1.f / (float)H_HEADS;
#pragma unroll
    for (int i = 0; i < PER; ++i) {
        const int c = i * 256 + tid;
        const float v = bf2f(ar[c]) * invH + bias[c];
        vals[i] = v;
        s1 += v;
        s2 += v * v;
    }
    __shared__ float red[2][4];
    for (int o = 32; o; o >>= 1) { s1 += __shfl_down(s1, o); s2 += __shfl_down(s2, o); }
    if ((tid & 63) == 0) { red[0][tid >> 6] = s1; red[1][tid >> 6] = s2; }
    __syncthreads();
    const float t1 = red[0][0] + red[0][1] + red[0][2] + red[0][3];
    const float t2 = red[1][0] + red[1][1] + red[1][2] + red[1][3];
    const float mu = t1 / C;
    const float var = t2 / C - mu * mu;
    const float rstd = rsqrtf(var + LN_EPS);
    u16* xr = xout + (size_t)n * C;
#pragma unroll
    for (int i = 0; i < PER; ++i) {
        const int c = i * 256 + tid;
        xr[c] = f2bf((vals[i] - mu) * rstd * g[c] + b[c]);
    }
}

// ---------------- segmented atomic mean-pool: grid (G, S), block C/4 ----------------
// out must be pre-zeroed; each block adds partial_sum * inv via atomicAdd.

template <int C, int S>
__global__ void pool_atomic(const u16* __restrict__ x, const int* __restrict__ goff,
                            float* __restrict__ out, int layer) {
    const int g = blockIdx.x, seg = blockIdx.y;
    const int beg = goff[g], end = goff[g + 1];
    const int len = end - beg;
    const int s0 = beg + (len * seg) / S;
    const int s1 = beg + (len * (seg + 1)) / S;
    if (s0 >= s1) return;
    const float inv = 1.f / fmaxf((float)len, 1.f);
    const int tid = threadIdx.x;  // 0..C/4-1
    float a0 = 0.f, a1 = 0.f, a2 = 0.f, a3 = 0.f;
    for (int n = s0; n < s1; ++n) {
        const ushort4v v = *(const ushort4v*)(x + (size_t)n * C + tid * 4);
        a0 += bf2f(v.x); a1 += bf2f(v.y); a2 += bf2f(v.z); a3 += bf2f(v.w);
    }
    float* o = out + ((size_t)g * (LAYERS + 1) + layer) * C + tid * 4;
    atomicAdd(o + 0, a0 * inv);
    atomicAdd(o + 1, a1 * inv);
    atomicAdd(o + 2, a2 * inv);
    atomicAdd(o + 3, a3 * inv);
}

// ---------------- launch ----------------

extern "C" void kernel_launch(void* const* d_in, const int* in_sizes, int n_in, void* d_out,
                              int out_size, void* d_ws, size_t ws_size, hipStream_t stream) {
    const int* drug_x      = (const int*)d_in[0];
    const int* mol_ei      = (const int*)d_in[1];
    const int* mol_batch   = (const int*)d_in[2];
    const float* prot_in   = (const float*)d_in[3];
    const int* prot_ei     = (const int*)d_in[4];
    const int* prot_batch  = (const int*)d_in[5];
    const float* emb       = (const float*)d_in[6];
    const float* mol_W     = (const float*)d_in[7];
    const float* mol_asrc  = (const float*)d_in[8];
    const float* mol_adst  = (const float*)d_in[9];
    const float* mol_bias  = (const float*)d_in[10];
    const float* mol_lng   = (const float*)d_in[11];
    const float* mol_lnb   = (const float*)d_in[12];
    const float* prot_W    = (const float*)d_in[13];
    const float* prot_asrc = (const float*)d_in[14];
    const float* prot_adst = (const float*)d_in[15];
    const float* prot_bias = (const float*)d_in[16];
    const float* prot_lng  = (const float*)d_in[17];
    const float* prot_lnb  = (const float*)d_in[18];

    if (ws_size < (size_t)157000000) return;  // proven budget from R2

    char* base = (char*)d_ws;
    size_t off = 0;
    auto alloc = [&](size_t bytes) -> void* {
        void* r = base + off;
        off = (off + bytes + 255) & ~(size_t)255;
        return r;
    };
    u16* x_mol  = (u16*)alloc((size_t)N_MOL * C_MOL * 2);
    u16* x_prot = (u16*)alloc((size_t)N_PROT * C_PROT * 2);
    u16* aggH   = (u16*)alloc((size_t)N_MOL * C_MOL * 2);
    u16* outb   = (u16*)alloc((size_t)N_MOL * C_MOL * 2);
    u16* Wt     = (u16*)alloc((size_t)H_HEADS * C_PROT * C_PROT * 2);
    float* wsrc = (float*)alloc((size_t)H_HEADS * C_PROT * 4);
    float* wdst = (float*)alloc((size_t)H_HEADS * C_PROT * 4);
    float* als  = (float*)alloc((size_t)N_MOL * H_HEADS * 4);
    float* ald  = (float*)alloc((size_t)N_MOL * H_HEADS * 4);
    float* alphaw = (float*)alloc((size_t)(E_MOL + N_MOL) * H_HEADS * 4);
    int* mol_indptr  = (int*)alloc((N_MOL + 1) * 4);
    int* mol_pos     = (int*)alloc(N_MOL * 4);
    int* mol_srcl    = (int*)alloc((E_MOL + N_MOL) * 4);
    int* prot_indptr = (int*)alloc((N_PROT + 1) * 4);
    int* prot_pos    = (int*)alloc(N_PROT * 4);
    int* prot_srcl   = (int*)alloc((E_PROT + N_PROT) * 4);
    int* cnt         = (int*)alloc(N_MOL * 4);
    int* mol_goff    = (int*)alloc((G_MOL + 1) * 4);
    int* prot_goff   = (int*)alloc((G_PROT + 1) * 4);
    int* gcnt        = (int*)alloc(G_MOL * 4);

    float* out_mol  = (float*)d_out;
    float* out_prot = (float*)d_out + (size_t)G_MOL * (LAYERS + 1) * C_MOL;

    // zero output (atomic pool accumulates into it)
    zero_f32_kernel<<<(out_size + 255) / 256, 256, 0, stream>>>((float*)d_out, out_size);

    // ---- CSR (incoming lists incl. self loops) ----
    set_int_kernel<<<(N_MOL + 255) / 256, 256, 0, stream>>>(cnt, 1, N_MOL);
    hist_kernel<<<(E_MOL + 255) / 256, 256, 0, stream>>>(mol_ei + E_MOL, E_MOL, cnt);
    scan_kernel<<<1, 1024, 0, stream>>>(cnt, mol_indptr, N_MOL);
    copy_int_kernel<<<(N_MOL + 255) / 256, 256, 0, stream>>>(mol_indptr, mol_pos, N_MOL);
    fill_self_kernel<<<(N_MOL + 255) / 256, 256, 0, stream>>>(mol_pos, mol_srcl, N_MOL);
    fill_edge_kernel<<<(E_MOL + 255) / 256, 256, 0, stream>>>(mol_ei, mol_ei + E_MOL, E_MOL, mol_pos,
                                                              mol_srcl);

    set_int_kernel<<<(N_PROT + 255) / 256, 256, 0, stream>>>(cnt, 1, N_PROT);
    hist_kernel<<<(E_PROT + 255) / 256, 256, 0, stream>>>(prot_ei + E_PROT, E_PROT, cnt);
    scan_kernel<<<1, 1024, 0, stream>>>(cnt, prot_indptr, N_PROT);
    copy_int_kernel<<<(N_PROT + 255) / 256, 256, 0, stream>>>(prot_indptr, prot_pos, N_PROT);
    fill_self_kernel<<<(N_PROT + 255) / 256, 256, 0, stream>>>(prot_pos, prot_srcl, N_PROT);
    fill_edge_kernel<<<(E_PROT + 255) / 256, 256, 0, stream>>>(prot_ei, prot_ei + E_PROT, E_PROT,
                                                               prot_pos, prot_srcl);

    // ---- graph offsets for pooling (batch sorted) ----
    set_int_kernel<<<(G_MOL + 255) / 256, 256, 0, stream>>>(gcnt, 0, G_MOL);
    hist_kernel<<<(N_MOL + 255) / 256, 256, 0, stream>>>(mol_batch, N_MOL, gcnt);
    scan_kernel<<<1, 1024, 0, stream>>>(gcnt, mol_goff, G_MOL);
    set_int_kernel<<<(G_PROT + 255) / 256, 256, 0, stream>>>(gcnt, 0, G_PROT);
    hist_kernel<<<(N_PROT + 255) / 256, 256, 0, stream>>>(prot_batch, N_PROT, gcnt);
    scan_kernel<<<1, 1024, 0, stream>>>(gcnt, prot_goff, G_PROT);

    // ---- layer-0 features ----
    f32_to_bf16<<<(N_PROT * C_PROT + 255) / 256, 256, 0, stream>>>(prot_in, x_prot, N_PROT * C_PROT);
    embed_mean_kernel<<<N_MOL, C_MOL, 0, stream>>>(drug_x, emb, x_mol);
    pool_atomic<C_MOL, 8><<<dim3(G_MOL, 8), C_MOL / 4, 0, stream>>>(x_mol, mol_goff, out_mol, 0);
    pool_atomic<C_PROT, 64><<<dim3(G_PROT, 64), C_PROT / 4, 0, stream>>>(x_prot, prot_goff, out_prot, 0);

    for (int l = 0; l < LAYERS; ++l) {
        // ---- molecule branch ----
        {
            const float* Wl = mol_W + (size_t)l * C_MOL * (H_HEADS * C_MOL);
            fold_attn<C_MOL, C_MOL><<<C_MOL, 256, 0, stream>>>(
                Wl, mol_asrc + (size_t)l * H_HEADS * C_MOL, mol_adst + (size_t)l * H_HEADS * C_MOL,
                wsrc, wdst);
            transposeW<C_MOL, C_MOL><<<dim3(C_MOL / 32, C_MOL / 32, H_HEADS), 256, 0, stream>>>(Wl, Wt);
            attn_logits<C_MOL><<<N_MOL, 64, 0, stream>>>(x_mol, wsrc, wdst, als, ald);
            alpha_kernel<<<N_MOL, 64, 0, stream>>>(als, ald, mol_indptr, mol_srcl, alphaw);
            for (int h = 0; h < H_HEADS; ++h) {
                aggregate_head<C_MOL><<<N_MOL, C_MOL / 4, 0, stream>>>(x_mol, alphaw, mol_indptr,
                                                                       mol_srcl, h, aggH);
                const u16* Bh = Wt + (size_t)h * C_MOL * C_MOL;
                if (h == 0)
                    gemm_mfma<0><<<dim3(C_MOL / 256, N_MOL / 64), 256, 0, stream>>>(
                        aggH, Bh, outb, N_MOL, C_MOL, C_MOL);
                else
                    gemm_mfma<1><<<dim3(C_MOL / 256, N_MOL / 64), 256, 0, stream>>>(
                        aggH, Bh, outb, N_MOL, C_MOL, C_MOL);
            }
            ln_kernel<C_MOL><<<N_MOL, 256, 0, stream>>>(outb, mol_bias + (size_t)l * C_MOL,
                                                        mol_lng + (size_t)l * C_MOL,
                                                        mol_lnb + (size_t)l * C_MOL, x_mol);
            pool_atomic<C_MOL, 8><<<dim3(G_MOL, 8), C_MOL / 4, 0, stream>>>(x_mol, mol_goff, out_mol,
                                                                            l + 1);
        }
        // ---- protein branch ----
        {
            const float* Wl = prot_W + (size_t)l * C_PROT * (H_HEADS * C_PROT);
            fold_attn<C_PROT, C_PROT><<<C_PROT, 256, 0, stream>>>(
                Wl, prot_asrc + (size_t)l * H_HEADS * C_PROT,
                prot_adst + (size_t)l * H_HEADS * C_PROT, wsrc, wdst);
            transposeW<C_PROT, C_PROT><<<dim3(C_PROT / 32, C_PROT / 32, H_HEADS), 256, 0, stream>>>(
                Wl, Wt);
            attn_logits<C_PROT><<<N_PROT, 64, 0, stream>>>(x_prot, wsrc, wdst, als, ald);
            alpha_kernel<<<N_PROT, 64, 0, stream>>>(als, ald, prot_indptr, prot_srcl, alphaw);
            for (int h = 0; h < H_HEADS; ++h) {
                aggregate_head<C_PROT><<<N_PROT, C_PROT / 4, 0, stream>>>(x_prot, alphaw, prot_indptr,
                                                                          prot_srcl, h, aggH);
                const u16* Bh = Wt + (size_t)h * C_PROT * C_PROT;
                if (h == 0)
                    gemm_mfma<0><<<dim3(C_PROT / 256, N_PROT / 64), 256, 0, stream>>>(
                        aggH, Bh, outb, N_PROT, C_PROT, C_PROT);
                else
                    gemm_mfma<1><<<dim3(C_PROT / 256, N_PROT / 64), 256, 0, stream>>>(
                        aggH, Bh, outb, N_PROT, C_PROT, C_PROT);
            }
            ln_kernel<C_PROT><<<N_PROT, 256, 0, stream>>>(outb, prot_bias + (size_t)l * C_PROT,
                                                          prot_lng + (size_t)l * C_PROT,
                                                          prot_lnb + (size_t)l * C_PROT, x_prot);
            pool_atomic<C_PROT, 64><<<dim3(G_PROT, 64), C_PROT / 4, 0, stream>>>(x_prot, prot_goff,
                                                                                 out_prot, l + 1);
        }
    }
}

// Round 4
// 2372.066 us; speedup vs baseline: 2.9367x; 2.2627x over previous
//
#include <hip/hip_runtime.h>
#include <cstdint>

// R4: GEMM was write-amplification-bound (WRITE 220MB vs 41MB tile, MfmaUtil 5.8%).
// Big-ws path (>=240MB): merged K=3C single GEMM per layer (no BETA), 128x128 tile,
// global_load_lds(16B) + XOR-swizzled LDS, LDS-staged coalesced C-write,
// fused aggregate_all3. Fallback (157..240MB): proven R3 path.

constexpr int H_HEADS = 3;
constexpr float NEG_SLOPE = 0.2f;
constexpr float LN_EPS = 1e-5f;
constexpr int N_MOL = 40000, E_MOL = 80000, C_MOL = 512, G_MOL = 512;
constexpr int N_PROT = 8000, E_PROT = 64000, C_PROT = 1280, G_PROT = 32;
constexpr int LAYERS = 4;
constexpr int MPAD_MOL = 40064;   // next multiple of 128
constexpr int MPAD_PROT = 8064;

typedef unsigned short u16;
typedef __attribute__((ext_vector_type(8))) short short8v;
typedef __attribute__((ext_vector_type(4))) unsigned short ushort4v;
typedef __attribute__((ext_vector_type(4))) float f32x4;

__device__ __forceinline__ float bf2f(u16 s) {
    union { unsigned u; float f; } v; v.u = ((unsigned)s) << 16; return v.f;
}
__device__ __forceinline__ u16 f2bf(float f) {
    union { float f; unsigned u; } v; v.f = f;
    return (u16)((v.u + 0x7fffu + ((v.u >> 16) & 1u)) >> 16);
}

__device__ __forceinline__ void g2l16(const void* g, void* l) {
    __builtin_amdgcn_global_load_lds((const __attribute__((address_space(1))) void*)g,
                                     (__attribute__((address_space(3))) void*)l, 16, 0, 0);
}

// ---------------- small utility kernels ----------------

__global__ void set_int_kernel(int* p, int v, int n) {
    int i = blockIdx.x * blockDim.x + threadIdx.x;
    if (i < n) p[i] = v;
}

__global__ void zero_f32_kernel(float* p, int n) {
    int i = blockIdx.x * blockDim.x + threadIdx.x;
    if (i < n) p[i] = 0.f;
}

__global__ void copy_int_kernel(const int* __restrict__ s, int* __restrict__ d, int n) {
    int i = blockIdx.x * blockDim.x + threadIdx.x;
    if (i < n) d[i] = s[i];
}

__global__ void hist_kernel(const int* __restrict__ keys, int n, int* __restrict__ cnt) {
    int i = blockIdx.x * blockDim.x + threadIdx.x;
    if (i < n) atomicAdd(&cnt[keys[i]], 1);
}

__global__ void scan_kernel(const int* __restrict__ in, int* __restrict__ out, int n) {
    __shared__ int sums[1024];
    const int t = threadIdx.x;
    const int chunk = (n + 1023) / 1024;
    const int start = t * chunk;
    const int end = min(start + chunk, n);
    int s = 0;
    for (int i = start; i < end; ++i) s += in[i];
    sums[t] = s;
    __syncthreads();
    if (t == 0) {
        int acc = 0;
        for (int i = 0; i < 1024; ++i) { int v = sums[i]; sums[i] = acc; acc += v; }
        out[n] = acc;
    }
    __syncthreads();
    int acc = sums[t];
    for (int i = start; i < end; ++i) { out[i] = acc; acc += in[i]; }
}

__global__ void fill_self_kernel(int* __restrict__ pos, int* __restrict__ srcl, int n) {
    int i = blockIdx.x * blockDim.x + threadIdx.x;
    if (i < n) { int slot = atomicAdd(&pos[i], 1); srcl[slot] = i; }
}

__global__ void fill_edge_kernel(const int* __restrict__ src, const int* __restrict__ dst, int e,
                                 int* __restrict__ pos, int* __restrict__ srcl) {
    int i = blockIdx.x * blockDim.x + threadIdx.x;
    if (i < e) { int slot = atomicAdd(&pos[dst[i]], 1); srcl[slot] = src[i]; }
}

__global__ void f32_to_bf16(const float* __restrict__ in, u16* __restrict__ out, int n) {
    int i = blockIdx.x * blockDim.x + threadIdx.x;
    if (i < n) out[i] = f2bf(in[i]);
}

// ---------------- embedding mean -> bf16 ----------------

__global__ void embed_mean_kernel(const int* __restrict__ drug_x, const float* __restrict__ emb,
                                  u16* __restrict__ out) {
    const int n = blockIdx.x;
    __shared__ int idx[9];
    if (threadIdx.x < 9) idx[threadIdx.x] = drug_x[n * 9 + threadIdx.x];
    __syncthreads();
    const int c = threadIdx.x;  // blockDim == C_MOL == 512
    float s = 0.f;
#pragma unroll
    for (int t = 0; t < 9; ++t) s += emb[(size_t)idx[t] * C_MOL + c];
    out[(size_t)n * C_MOL + c] = f2bf(s * (1.f / 9.f));
}

// ---------------- fold attention vectors ----------------

template <int CIN, int COUT>
__global__ __launch_bounds__(256) void fold_attn(const float* __restrict__ W,
                                                 const float* __restrict__ asrc,
                                                 const float* __restrict__ adst,
                                                 float* __restrict__ wsrc, float* __restrict__ wdst) {
    const int i = blockIdx.x;
    const int tid = threadIdx.x;
    __shared__ float rb[8];
    const float* Wr = W + (size_t)i * (H_HEADS * COUT);
    for (int h = 0; h < H_HEADS; ++h) {
        float ss = 0.f, sd = 0.f;
        for (int c = tid; c < COUT; c += 256) {
            const float w = Wr[h * COUT + c];
            ss += w * asrc[h * COUT + c];
            sd += w * adst[h * COUT + c];
        }
        for (int o = 32; o; o >>= 1) { ss += __shfl_down(ss, o); sd += __shfl_down(sd, o); }
        if ((tid & 63) == 0) { rb[tid >> 6] = ss; rb[4 + (tid >> 6)] = sd; }
        __syncthreads();
        if (tid == 0) {
            wsrc[h * CIN + i] = rb[0] + rb[1] + rb[2] + rb[3];
            wdst[h * CIN + i] = rb[4] + rb[5] + rb[6] + rb[7];
        }
        __syncthreads();
    }
}

// ---------------- weight transpose+convert (parameterized layout) ----------------
// Wt[h*headStride + n*ldn + k] = bf16(W[k][h*COUT + n])

__global__ __launch_bounds__(256) void transposeW(const float* __restrict__ W, u16* __restrict__ Wt,
                                                  int COUT, size_t headStride, int ldn) {
    __shared__ float t[32][33];
    const int h = blockIdx.z;
    const int n0 = blockIdx.x * 32, k0 = blockIdx.y * 32;
    const int tx = threadIdx.x & 31, ty = threadIdx.x >> 5;
#pragma unroll
    for (int q = 0; q < 4; ++q)
        t[ty + q * 8][tx] = W[(size_t)(k0 + ty + q * 8) * (H_HEADS * COUT) + h * COUT + n0 + tx];
    __syncthreads();
#pragma unroll
    for (int q = 0; q < 4; ++q)
        Wt[(size_t)h * headStride + (size_t)(n0 + ty + q * 8) * ldn + k0 + tx] =
            f2bf(t[tx][ty + q * 8]);
}

// ---------------- attention logits: one wave per node, vectorized ----------------

template <int C>
__global__ void attn_logits(const u16* __restrict__ x, const float* __restrict__ wsrc,
                            const float* __restrict__ wdst, float* __restrict__ als,
                            float* __restrict__ ald) {
    constexpr int PER = C / 64;
    const int n = blockIdx.x, lane = threadIdx.x;
    const u16* xr = x + (size_t)n * C + lane * PER;
    float xv[PER];
#pragma unroll
    for (int i = 0; i < PER; i += 4) {
        const ushort4v v = *(const ushort4v*)(xr + i);
        xv[i] = bf2f(v.x); xv[i + 1] = bf2f(v.y); xv[i + 2] = bf2f(v.z); xv[i + 3] = bf2f(v.w);
    }
    for (int h = 0; h < H_HEADS; ++h) {
        const float* ws = wsrc + h * C + lane * PER;
        const float* wd = wdst + h * C + lane * PER;
        float ss = 0.f, sd = 0.f;
#pragma unroll
        for (int i = 0; i < PER; i += 4) {
            const float4 a = *(const float4*)(ws + i);
            const float4 b = *(const float4*)(wd + i);
            ss += xv[i] * a.x + xv[i + 1] * a.y + xv[i + 2] * a.z + xv[i + 3] * a.w;
            sd += xv[i] * b.x + xv[i + 1] * b.y + xv[i + 2] * b.z + xv[i + 3] * b.w;
        }
        for (int o = 32; o; o >>= 1) { ss += __shfl_down(ss, o); sd += __shfl_down(sd, o); }
        if (lane == 0) { als[n * H_HEADS + h] = ss; ald[n * H_HEADS + h] = sd; }
    }
}

// ---------------- segment softmax -> alpha per CSR slot ----------------

__global__ void alpha_kernel(const float* __restrict__ als, const float* __restrict__ ald,
                             const int* __restrict__ indptr, const int* __restrict__ srcl,
                             float* __restrict__ alphaw) {
    const int n = blockIdx.x, lane = threadIdx.x;
    if (lane >= H_HEADS) return;
    const int beg = indptr[n], end = indptr[n + 1];
    const float ad = ald[n * H_HEADS + lane];
    float m = -1e30f;
    for (int e = beg; e < end; ++e) {
        float v = als[srcl[e] * H_HEADS + lane] + ad;
        v = v >= 0.f ? v : NEG_SLOPE * v;
        m = fmaxf(m, v);
    }
    float z = 0.f;
    for (int e = beg; e < end; ++e) {
        float v = als[srcl[e] * H_HEADS + lane] + ad;
        v = v >= 0.f ? v : NEG_SLOPE * v;
        z += __expf(v - m);
    }
    const float zi = 1.f / (z + 1e-16f);
    for (int e = beg; e < end; ++e) {
        float v = als[srcl[e] * H_HEADS + lane] + ad;
        v = v >= 0.f ? v : NEG_SLOPE * v;
        alphaw[e * H_HEADS + lane] = __expf(v - m) * zi;
    }
}

// ---------------- fallback: per-head aggregation ----------------

template <int C>
__global__ void aggregate_head(const u16* __restrict__ x, const float* __restrict__ alphaw,
                               const int* __restrict__ indptr, const int* __restrict__ srcl,
                               int head, u16* __restrict__ aggH) {
    const int n = blockIdx.x, tid = threadIdx.x;
    const int beg = indptr[n], end = indptr[n + 1];
    float a0 = 0.f, a1 = 0.f, a2 = 0.f, a3 = 0.f;
    for (int e = beg; e < end; ++e) {
        const float a = alphaw[e * H_HEADS + head];
        const ushort4v v = *(const ushort4v*)(x + (size_t)srcl[e] * C + tid * 4);
        a0 += a * bf2f(v.x); a1 += a * bf2f(v.y); a2 += a * bf2f(v.z); a3 += a * bf2f(v.w);
    }
    ushort4v r;
    r.x = f2bf(a0); r.y = f2bf(a1); r.z = f2bf(a2); r.w = f2bf(a3);
    *(ushort4v*)(aggH + (size_t)n * C + tid * 4) = r;
}

// ---------------- big path: all-3-head aggregation, writes [M][3C] interleaved ----------------

template <int C>
__global__ void aggregate_all3(const u16* __restrict__ x, const float* __restrict__ alphaw,
                               const int* __restrict__ indptr, const int* __restrict__ srcl,
                               u16* __restrict__ aggAll) {
    const int n = blockIdx.x, tid = threadIdx.x;  // block C/4
    const int beg = indptr[n], end = indptr[n + 1];
    float acc[H_HEADS][4];
#pragma unroll
    for (int h = 0; h < H_HEADS; ++h)
#pragma unroll
        for (int j = 0; j < 4; ++j) acc[h][j] = 0.f;
    for (int e = beg; e < end; ++e) {
        const float a0 = alphaw[e * H_HEADS + 0];
        const float a1 = alphaw[e * H_HEADS + 1];
        const float a2 = alphaw[e * H_HEADS + 2];
        const ushort4v v = *(const ushort4v*)(x + (size_t)srcl[e] * C + tid * 4);
        const float f0 = bf2f(v.x), f1 = bf2f(v.y), f2 = bf2f(v.z), f3 = bf2f(v.w);
        acc[0][0] += a0 * f0; acc[0][1] += a0 * f1; acc[0][2] += a0 * f2; acc[0][3] += a0 * f3;
        acc[1][0] += a1 * f0; acc[1][1] += a1 * f1; acc[1][2] += a1 * f2; acc[1][3] += a1 * f3;
        acc[2][0] += a2 * f0; acc[2][1] += a2 * f1; acc[2][2] += a2 * f2; acc[2][3] += a2 * f3;
    }
    u16* o = aggAll + (size_t)n * (3 * C) + tid * 4;
#pragma unroll
    for (int h = 0; h < H_HEADS; ++h) {
        ushort4v r;
        r.x = f2bf(acc[h][0]); r.y = f2bf(acc[h][1]); r.z = f2bf(acc[h][2]); r.w = f2bf(acc[h][3]);
        *(ushort4v*)(o + h * C) = r;
    }
}

// ---------------- fallback GEMM (R3, proven): 64x256 tile ----------------

template <int BETA>
__global__ __launch_bounds__(256) void gemm_mfma(const u16* __restrict__ A,
                                                 const u16* __restrict__ Bt,
                                                 u16* __restrict__ C, int M, int N, int K) {
    __shared__ u16 As[64][40];
    __shared__ u16 Bs[256][40];
    const int tid = threadIdx.x;
    const int w = tid >> 6;
    const int l = tid & 63;
    const int bm = blockIdx.y * 64;
    const int bn = blockIdx.x * 256;
    const f32x4 zf = {0.f, 0.f, 0.f, 0.f};
    f32x4 acc[4][4];
#pragma unroll
    for (int i = 0; i < 4; ++i)
#pragma unroll
        for (int j = 0; j < 4; ++j) acc[i][j] = zf;

    const int arow = tid >> 2, aseg = tid & 3;
    const u16* Ab = A + (size_t)(bm + arow) * K + aseg * 8;
    for (int k0 = 0; k0 < K; k0 += 32) {
        const float4 av = *(const float4*)(Ab + k0);
        float4 bv[4];
#pragma unroll
        for (int q = 0; q < 4; ++q) {
            const int c = q * 256 + tid;
            bv[q] = *(const float4*)(Bt + (size_t)(bn + (c >> 2)) * K + k0 + (c & 3) * 8);
        }
        __syncthreads();
        *(float4*)&As[arow][aseg * 8] = av;
#pragma unroll
        for (int q = 0; q < 4; ++q) {
            const int c = q * 256 + tid;
            *(float4*)&Bs[c >> 2][(c & 3) * 8] = bv[q];
        }
        __syncthreads();
        const int koff = 8 * (l >> 4);
        const int rl = l & 15;
        short8v af[4], bfr[4];
#pragma unroll
        for (int fm = 0; fm < 4; ++fm) af[fm] = *(const short8v*)&As[fm * 16 + rl][koff];
#pragma unroll
        for (int fn = 0; fn < 4; ++fn) bfr[fn] = *(const short8v*)&Bs[w * 64 + fn * 16 + rl][koff];
#pragma unroll
        for (int fm = 0; fm < 4; ++fm)
#pragma unroll
            for (int fn = 0; fn < 4; ++fn)
                acc[fm][fn] =
                    __builtin_amdgcn_mfma_f32_16x16x32_bf16(af[fm], bfr[fn], acc[fm][fn], 0, 0, 0);
    }
    const int r0 = (l >> 4) * 4;
    const int cn = l & 15;
#pragma unroll
    for (int fm = 0; fm < 4; ++fm)
#pragma unroll
        for (int fn = 0; fn < 4; ++fn) {
            u16* Cp = C + (size_t)(bm + fm * 16 + r0) * N + bn + w * 64 + fn * 16 + cn;
#pragma unroll
            for (int r = 0; r < 4; ++r) {
                float v = acc[fm][fn][r];
                if (BETA) v += bf2f(Cp[(size_t)r * N]);
                Cp[(size_t)r * N] = f2bf(v);
            }
        }
}

// ---------------- big path GEMM: 128x128 tile, BK=64, global_load_lds + swizzle ----------------
// A[M,K] row-major bf16, Bt[N,K] row-major bf16, C[M,N] bf16. M%128==0, N%128==0, K%64==0.
// LDS: As flat [128 rows][64 u16] at lds[0..8192), Bs at lds[8192..16384).
// Swizzle: content at (row, seg16B) = global seg (seg ^ (row&7)); linear dest for
// global_load_lds, inverse-swizzled global source (rule #21), swizzled ds_read (2-way free).

__global__ __launch_bounds__(256) void gemm_mfma128(const u16* __restrict__ A,
                                                    const u16* __restrict__ Bt,
                                                    u16* __restrict__ Cout,
                                                    int M, int N, int K) {
    __shared__ u16 lds[17408];  // 34816 B; epilogue restages C (stride 136 u16)
    const int tid = threadIdx.x;
    const int w = tid >> 6, l = tid & 63;
    const int wr = w >> 1, wc = w & 1;
    const size_t bm = (size_t)blockIdx.y * 128, bn = (size_t)blockIdx.x * 128;
    const f32x4 zf = {0.f, 0.f, 0.f, 0.f};
    f32x4 acc[4][4];
#pragma unroll
    for (int i = 0; i < 4; ++i)
#pragma unroll
        for (int j = 0; j < 4; ++j) acc[i][j] = zf;

    // staging geometry: chunk q of wave w covers rows w*32+q*8 .. +8, lane l -> (row +l>>3, seg l&7)
    const int srow = w * 32 + (l >> 3);   // q adds q*8 (doesn't change row&7)
    const int sseg = (l & 7) ^ (l >> 3);  // inverse-swizzled global segment
    const u16* Ab = A + (bm + srow) * (size_t)K + sseg * 8;
    const u16* Bb = Bt + (bn + srow) * (size_t)K + sseg * 8;

    for (int k0 = 0; k0 < K; k0 += 64) {
#pragma unroll
        for (int q = 0; q < 4; ++q)
            g2l16(Ab + k0 + (size_t)q * 8 * K, lds + (w * 4 + q) * 512);
#pragma unroll
        for (int q = 0; q < 4; ++q)
            g2l16(Bb + k0 + (size_t)q * 8 * K, lds + 8192 + (w * 4 + q) * 512);
        __syncthreads();
#pragma unroll
        for (int kk = 0; kk < 2; ++kk) {
            short8v af[4], bfr[4];
#pragma unroll
            for (int fm = 0; fm < 4; ++fm) {
                const int row = wr * 64 + fm * 16 + (l & 15);
                const int seg = (kk * 4 + (l >> 4)) ^ (row & 7);
                af[fm] = *(const short8v*)&lds[row * 64 + seg * 8];
            }
#pragma unroll
            for (int fn = 0; fn < 4; ++fn) {
                const int row = wc * 64 + fn * 16 + (l & 15);
                const int seg = (kk * 4 + (l >> 4)) ^ (row & 7);
                bfr[fn] = *(const short8v*)&lds[8192 + row * 64 + seg * 8];
            }
#pragma unroll
            for (int fm = 0; fm < 4; ++fm)
#pragma unroll
                for (int fn = 0; fn < 4; ++fn)
                    acc[fm][fn] = __builtin_amdgcn_mfma_f32_16x16x32_bf16(af[fm], bfr[fn],
                                                                          acc[fm][fn], 0, 0, 0);
        }
        __syncthreads();
    }

    // epilogue: stage C tile to LDS (stride 136 u16 to spread banks), coalesced write
#pragma unroll
    for (int fm = 0; fm < 4; ++fm) {
        const int row = wr * 64 + fm * 16 + (l >> 4) * 4;
#pragma unroll
        for (int fn = 0; fn < 4; ++fn) {
            const int col = wc * 64 + fn * 16 + (l & 15);
#pragma unroll
            for (int r = 0; r < 4; ++r) lds[(row + r) * 136 + col] = f2bf(acc[fm][fn][r]);
        }
    }
    __syncthreads();
    const int orow = tid >> 1, ohalf = tid & 1;  // 2 threads per row, 128B each
    u16* Crow = Cout + (bm + orow) * (size_t)N + bn + ohalf * 64;
    const u16* Lrow = lds + orow * 136 + ohalf * 64;
#pragma unroll
    for (int i = 0; i < 8; ++i)
        *(float4*)(Crow + i * 8) = *(const float4*)(Lrow + i * 8);
}

// ---------------- fused scale + bias + LayerNorm ----------------

template <int C>
__global__ __launch_bounds__(256) void ln_kernel(const u16* __restrict__ acc,
                                                 const float* __restrict__ bias,
                                                 const float* __restrict__ g,
                                                 const float* __restrict__ b,
                                                 u16* __restrict__ xout) {
    constexpr int PER = C / 256;
    const int n = blockIdx.x, tid = threadIdx.x;
    const u16* ar = acc + (size_t)n * C;
    float vals[PER];
    float s1 = 0.f, s2 = 0.f;
    constexpr float invH = 1.f / (float)H_HEADS;
#pragma unroll
    for (int i = 0; i < PER; ++i) {
        const int c = i * 256 + tid;
        const float v = bf2f(ar[c]) * invH + bias[c];
        vals[i] = v;
        s1 += v;
        s2 += v * v;
    }
    __shared__ float red[2][4];
    for (int o = 32; o; o >>= 1) { s1 += __shfl_down(s1, o); s2 += __shfl_down(s2, o); }
    if ((tid & 63) == 0) { red[0][tid >> 6] = s1; red[1][tid >> 6] = s2; }
    __syncthreads();
    const float t1 = red[0][0] + red[0][1] + red[0][2] + red[0][3];
    const float t2 = red[1][0] + red[1][1] + red[1][2] + red[1][3];
    const float mu = t1 / C;
    const float var = t2 / C - mu * mu;
    const float rstd = rsqrtf(var + LN_EPS);
    u16* xr = xout + (size_t)n * C;
#pragma unroll
    for (int i = 0; i < PER; ++i) {
        const int c = i * 256 + tid;
        xr[c] = f2bf((vals[i] - mu) * rstd * g[c] + b[c]);
    }
}

// ---------------- segmented atomic mean-pool ----------------

template <int C, int S>
__global__ void pool_atomic(const u16* __restrict__ x, const int* __restrict__ goff,
                            float* __restrict__ out, int layer) {
    const int g = blockIdx.x, seg = blockIdx.y;
    const int beg = goff[g], end = goff[g + 1];
    const int len = end - beg;
    const int s0 = beg + (len * seg) / S;
    const int s1 = beg + (len * (seg + 1)) / S;
    if (s0 >= s1) return;
    const float inv = 1.f / fmaxf((float)len, 1.f);
    const int tid = threadIdx.x;
    float a0 = 0.f, a1 = 0.f, a2 = 0.f, a3 = 0.f;
    for (int n = s0; n < s1; ++n) {
        const ushort4v v = *(const ushort4v*)(x + (size_t)n * C + tid * 4);
        a0 += bf2f(v.x); a1 += bf2f(v.y); a2 += bf2f(v.z); a3 += bf2f(v.w);
    }
    float* o = out + ((size_t)g * (LAYERS + 1) + layer) * C + tid * 4;
    atomicAdd(o + 0, a0 * inv);
    atomicAdd(o + 1, a1 * inv);
    atomicAdd(o + 2, a2 * inv);
    atomicAdd(o + 3, a3 * inv);
}

// ---------------- launch ----------------

extern "C" void kernel_launch(void* const* d_in, const int* in_sizes, int n_in, void* d_out,
                              int out_size, void* d_ws, size_t ws_size, hipStream_t stream) {
    const int* drug_x      = (const int*)d_in[0];
    const int* mol_ei      = (const int*)d_in[1];
    const int* mol_batch   = (const int*)d_in[2];
    const float* prot_in   = (const float*)d_in[3];
    const int* prot_ei     = (const int*)d_in[4];
    const int* prot_batch  = (const int*)d_in[5];
    const float* emb       = (const float*)d_in[6];
    const float* mol_W     = (const float*)d_in[7];
    const float* mol_asrc  = (const float*)d_in[8];
    const float* mol_adst  = (const float*)d_in[9];
    const float* mol_bias  = (const float*)d_in[10];
    const float* mol_lng   = (const float*)d_in[11];
    const float* mol_lnb   = (const float*)d_in[12];
    const float* prot_W    = (const float*)d_in[13];
    const float* prot_asrc = (const float*)d_in[14];
    const float* prot_adst = (const float*)d_in[15];
    const float* prot_bias = (const float*)d_in[16];
    const float* prot_lng  = (const float*)d_in[17];
    const float* prot_lnb  = (const float*)d_in[18];

    if (ws_size < (size_t)157000000) return;            // below proven budget: no-op
    const bool BIG = ws_size >= (size_t)240500000;      // merged-GEMM path budget (~239.2MB)

    char* base = (char*)d_ws;
    size_t off = 0;
    auto alloc = [&](size_t bytes) -> void* {
        void* r = base + off;
        off = (off + bytes + 255) & ~(size_t)255;
        return r;
    };
    // common
    u16* x_mol  = (u16*)alloc((size_t)N_MOL * C_MOL * 2);
    u16* x_prot = (u16*)alloc((size_t)N_PROT * C_PROT * 2);
    u16* Wt     = (u16*)alloc((size_t)H_HEADS * C_PROT * C_PROT * 2);
    float* wsrc = (float*)alloc((size_t)H_HEADS * C_PROT * 4);
    float* wdst = (float*)alloc((size_t)H_HEADS * C_PROT * 4);
    float* als  = (float*)alloc((size_t)N_MOL * H_HEADS * 4);
    float* ald  = (float*)alloc((size_t)N_MOL * H_HEADS * 4);
    float* alphaw = (float*)alloc((size_t)(E_MOL + N_MOL) * H_HEADS * 4);
    int* mol_indptr  = (int*)alloc((N_MOL + 1) * 4);
    int* mol_pos     = (int*)alloc(N_MOL * 4);
    int* mol_srcl    = (int*)alloc((E_MOL + N_MOL) * 4);
    int* prot_indptr = (int*)alloc((N_PROT + 1) * 4);
    int* prot_pos    = (int*)alloc(N_PROT * 4);
    int* prot_srcl   = (int*)alloc((E_PROT + N_PROT) * 4);
    int* cnt         = (int*)alloc(N_MOL * 4);
    int* mol_goff    = (int*)alloc((G_MOL + 1) * 4);
    int* prot_goff   = (int*)alloc((G_PROT + 1) * 4);
    int* gcnt        = (int*)alloc(G_MOL * 4);
    // path-specific
    u16 *aggAll = nullptr, *aggH = nullptr, *outb = nullptr;
    if (BIG) {
        aggAll = (u16*)alloc((size_t)3 * MPAD_MOL * C_MOL * 2);   // 123.1 MB (>= prot need)
        outb   = (u16*)alloc((size_t)MPAD_MOL * C_MOL * 2);       // 41.0 MB (>= prot need)
    } else {
        aggH = (u16*)alloc((size_t)N_MOL * C_MOL * 2);
        outb = (u16*)alloc((size_t)N_MOL * C_MOL * 2);
    }

    float* out_mol  = (float*)d_out;
    float* out_prot = (float*)d_out + (size_t)G_MOL * (LAYERS + 1) * C_MOL;

    zero_f32_kernel<<<(out_size + 255) / 256, 256, 0, stream>>>((float*)d_out, out_size);

    // ---- CSR (incoming lists incl. self loops) ----
    set_int_kernel<<<(N_MOL + 255) / 256, 256, 0, stream>>>(cnt, 1, N_MOL);
    hist_kernel<<<(E_MOL + 255) / 256, 256, 0, stream>>>(mol_ei + E_MOL, E_MOL, cnt);
    scan_kernel<<<1, 1024, 0, stream>>>(cnt, mol_indptr, N_MOL);
    copy_int_kernel<<<(N_MOL + 255) / 256, 256, 0, stream>>>(mol_indptr, mol_pos, N_MOL);
    fill_self_kernel<<<(N_MOL + 255) / 256, 256, 0, stream>>>(mol_pos, mol_srcl, N_MOL);
    fill_edge_kernel<<<(E_MOL + 255) / 256, 256, 0, stream>>>(mol_ei, mol_ei + E_MOL, E_MOL, mol_pos,
                                                              mol_srcl);

    set_int_kernel<<<(N_PROT + 255) / 256, 256, 0, stream>>>(cnt, 1, N_PROT);
    hist_kernel<<<(E_PROT + 255) / 256, 256, 0, stream>>>(prot_ei + E_PROT, E_PROT, cnt);
    scan_kernel<<<1, 1024, 0, stream>>>(cnt, prot_indptr, N_PROT);
    copy_int_kernel<<<(N_PROT + 255) / 256, 256, 0, stream>>>(prot_indptr, prot_pos, N_PROT);
    fill_self_kernel<<<(N_PROT + 255) / 256, 256, 0, stream>>>(prot_pos, prot_srcl, N_PROT);
    fill_edge_kernel<<<(E_PROT + 255) / 256, 256, 0, stream>>>(prot_ei, prot_ei + E_PROT, E_PROT,
                                                               prot_pos, prot_srcl);

    // ---- graph offsets for pooling ----
    set_int_kernel<<<(G_MOL + 255) / 256, 256, 0, stream>>>(gcnt, 0, G_MOL);
    hist_kernel<<<(N_MOL + 255) / 256, 256, 0, stream>>>(mol_batch, N_MOL, gcnt);
    scan_kernel<<<1, 1024, 0, stream>>>(gcnt, mol_goff, G_MOL);
    set_int_kernel<<<(G_PROT + 255) / 256, 256, 0, stream>>>(gcnt, 0, G_PROT);
    hist_kernel<<<(N_PROT + 255) / 256, 256, 0, stream>>>(prot_batch, N_PROT, gcnt);
    scan_kernel<<<1, 1024, 0, stream>>>(gcnt, prot_goff, G_PROT);

    // ---- layer-0 features ----
    f32_to_bf16<<<(N_PROT * C_PROT + 255) / 256, 256, 0, stream>>>(prot_in, x_prot, N_PROT * C_PROT);
    embed_mean_kernel<<<N_MOL, C_MOL, 0, stream>>>(drug_x, emb, x_mol);
    pool_atomic<C_MOL, 8><<<dim3(G_MOL, 8), C_MOL / 4, 0, stream>>>(x_mol, mol_goff, out_mol, 0);
    pool_atomic<C_PROT, 64><<<dim3(G_PROT, 64), C_PROT / 4, 0, stream>>>(x_prot, prot_goff, out_prot, 0);

    for (int l = 0; l < LAYERS; ++l) {
        // ---- molecule branch ----
        {
            const float* Wl = mol_W + (size_t)l * C_MOL * (H_HEADS * C_MOL);
            fold_attn<C_MOL, C_MOL><<<C_MOL, 256, 0, stream>>>(
                Wl, mol_asrc + (size_t)l * H_HEADS * C_MOL, mol_adst + (size_t)l * H_HEADS * C_MOL,
                wsrc, wdst);
            attn_logits<C_MOL><<<N_MOL, 64, 0, stream>>>(x_mol, wsrc, wdst, als, ald);
            alpha_kernel<<<N_MOL, 64, 0, stream>>>(als, ald, mol_indptr, mol_srcl, alphaw);
            if (BIG) {
                transposeW<<<dim3(C_MOL / 32, C_MOL / 32, H_HEADS), 256, 0, stream>>>(
                    Wl, Wt, C_MOL, (size_t)C_MOL, 3 * C_MOL);
                aggregate_all3<C_MOL><<<N_MOL, C_MOL / 4, 0, stream>>>(x_mol, alphaw, mol_indptr,
                                                                       mol_srcl, aggAll);
                gemm_mfma128<<<dim3(C_MOL / 128, MPAD_MOL / 128), 256, 0, stream>>>(
                    aggAll, Wt, outb, MPAD_MOL, C_MOL, 3 * C_MOL);
            } else {
                transposeW<<<dim3(C_MOL / 32, C_MOL / 32, H_HEADS), 256, 0, stream>>>(
                    Wl, Wt, C_MOL, (size_t)C_MOL * C_MOL, C_MOL);
                for (int h = 0; h < H_HEADS; ++h) {
                    aggregate_head<C_MOL><<<N_MOL, C_MOL / 4, 0, stream>>>(x_mol, alphaw, mol_indptr,
                                                                           mol_srcl, h, aggH);
                    const u16* Bh = Wt + (size_t)h * C_MOL * C_MOL;
                    if (h == 0)
                        gemm_mfma<0><<<dim3(C_MOL / 256, N_MOL / 64), 256, 0, stream>>>(
                            aggH, Bh, outb, N_MOL, C_MOL, C_MOL);
                    else
                        gemm_mfma<1><<<dim3(C_MOL / 256, N_MOL / 64), 256, 0, stream>>>(
                            aggH, Bh, outb, N_MOL, C_MOL, C_MOL);
                }
            }
            ln_kernel<C_MOL><<<N_MOL, 256, 0, stream>>>(outb, mol_bias + (size_t)l * C_MOL,
                                                        mol_lng + (size_t)l * C_MOL,
                                                        mol_lnb + (size_t)l * C_MOL, x_mol);
            pool_atomic<C_MOL, 8><<<dim3(G_MOL, 8), C_MOL / 4, 0, stream>>>(x_mol, mol_goff, out_mol,
                                                                            l + 1);
        }
        // ---- protein branch ----
        {
            const float* Wl = prot_W + (size_t)l * C_PROT * (H_HEADS * C_PROT);
            fold_attn<C_PROT, C_PROT><<<C_PROT, 256, 0, stream>>>(
                Wl, prot_asrc + (size_t)l * H_HEADS * C_PROT,
                prot_adst + (size_t)l * H_HEADS * C_PROT, wsrc, wdst);
            attn_logits<C_PROT><<<N_PROT, 64, 0, stream>>>(x_prot, wsrc, wdst, als, ald);
            alpha_kernel<<<N_PROT, 64, 0, stream>>>(als, ald, prot_indptr, prot_srcl, alphaw);
            if (BIG) {
                transposeW<<<dim3(C_PROT / 32, C_PROT / 32, H_HEADS), 256, 0, stream>>>(
                    Wl, Wt, C_PROT, (size_t)C_PROT, 3 * C_PROT);
                aggregate_all3<C_PROT><<<N_PROT, C_PROT / 4, 0, stream>>>(x_prot, alphaw, prot_indptr,
                                                                          prot_srcl, aggAll);
                gemm_mfma128<<<dim3(C_PROT / 128, MPAD_PROT / 128), 256, 0, stream>>>(
                    aggAll, Wt, outb, MPAD_PROT, C_PROT, 3 * C_PROT);
            } else {
                transposeW<<<dim3(C_PROT / 32, C_PROT / 32, H_HEADS), 256, 0, stream>>>(
                    Wl, Wt, C_PROT, (size_t)C_PROT * C_PROT, C_PROT);
                for (int h = 0; h < H_HEADS; ++h) {
                    aggregate_head<C_PROT><<<N_PROT, C_PROT / 4, 0, stream>>>(
                        x_prot, alphaw, prot_indptr, prot_srcl, h, aggH);
                    const u16* Bh = Wt + (size_t)h * C_PROT * C_PROT;
                    if (h == 0)
                        gemm_mfma<0><<<dim3(C_PROT / 256, N_PROT / 64), 256, 0, stream>>>(
                            aggH, Bh, outb, N_PROT, C_PROT, C_PROT);
                    else
                        gemm_mfma<1><<<dim3(C_PROT / 256, N_PROT / 64), 256, 0, stream>>>(
                            aggH, Bh, outb, N_PROT, C_PROT, C_PROT);
                }
            }
            ln_kernel<C_PROT><<<N_PROT, 256, 0, stream>>>(outb, prot_bias + (size_t)l * C_PROT,
                                                          prot_lng + (size_t)l * C_PROT,
                                                          prot_lnb + (size_t)l * C_PROT, x_prot);
            pool_atomic<C_PROT, 64><<<dim3(G_PROT, 64), C_PROT / 4, 0, stream>>>(x_prot, prot_goff,
                                                                                 out_prot, l + 1);
        }
    }
}